// Round 4
// baseline (417.588 us; speedup 1.0000x reference)
//
#include <hip/hip_runtime.h>

#define DIM 64

// ---------------- CSR build ----------------

__global__ __launch_bounds__(256)
void count_kernel(const int* __restrict__ dst, int* __restrict__ counts, int nE) {
    int e = blockIdx.x * 256 + threadIdx.x;
    if (e < nE) atomicAdd(&counts[dst[e]], 1);
}

__global__ __launch_bounds__(1024)
void scan_kernel(const int* __restrict__ counts, int* __restrict__ rowStart,
                 int* __restrict__ cursor, int n) {
    __shared__ int part[1024];
    int t = threadIdx.x;
    int chunk = (n + 1023) >> 10;
    int beg = min(t * chunk, n);
    int end = min(beg + chunk, n);
    int s = 0;
    for (int i = beg; i < end; ++i) s += counts[i];
    part[t] = s;
    __syncthreads();
    for (int off = 1; off < 1024; off <<= 1) {
        int v = (t >= off) ? part[t - off] : 0;
        __syncthreads();
        part[t] += v;
        __syncthreads();
    }
    int run = (t == 0) ? 0 : part[t - 1];
    for (int i = beg; i < end; ++i) {
        rowStart[i] = run;
        cursor[i] = run;
        run += counts[i];
    }
    if (t == 0) rowStart[n] = part[1023];
}

__global__ __launch_bounds__(256)
void permute_kernel(const int* __restrict__ ei, int* __restrict__ cursor,
                    int2* __restrict__ perm, int nE) {
    int e = blockIdx.x * 256 + threadIdx.x;
    if (e >= nE) return;
    int s = ei[e];
    int t = ei[nE + e];
    int pos = atomicAdd(&cursor[t], 1);
    perm[pos] = make_int2(s, e);
}

// ---------------- fused gather + MLP ----------------
// One node per wave. Lane layout: grp = lane>>4 (edge slot), dl = lane&15 (dim quad).
// Key: ONE coalesced perm[beg+lane] load covers up to 64 edges; (src,eid) are then
// distributed in-register via shfl, so all 256B gathers issue back-to-back with no
// interleaved dependent perm loads.
__global__ __launch_bounds__(256)
void gather_mlp_kernel(const float4* __restrict__ x4, const float4* __restrict__ ea4,
                       const int2* __restrict__ perm, const int* __restrict__ rowStart,
                       const float* __restrict__ epsL,
                       const float* __restrict__ W1, const float* __restrict__ b1,
                       const float* __restrict__ W2, const float* __restrict__ b2,
                       float* __restrict__ out, int nNodes) {
    __shared__ float sW1[DIM * DIM];
    __shared__ float sW2[DIM * DIM];
    __shared__ float sb1[DIM];
    __shared__ float sb2[DIM];
    for (int i = threadIdx.x; i < DIM * DIM; i += blockDim.x) {
        sW1[i] = W1[i];
        sW2[i] = W2[i];
    }
    if (threadIdx.x < DIM) {
        sb1[threadIdx.x] = b1[threadIdx.x];
        sb2[threadIdx.x] = b2[threadIdx.x];
    }
    __syncthreads();

    const int lane = threadIdx.x & 63;
    const int wave = threadIdx.x >> 6;
    const int grp  = lane >> 4;
    const int dl   = lane & 15;
    const int wavesPerBlock = blockDim.x >> 6;
    const int wavesTotal = gridDim.x * wavesPerBlock;
    const float eps1 = 1.0f + epsL[0];

    for (int node = blockIdx.x * wavesPerBlock + wave; node < nNodes; node += wavesTotal) {
        int beg = rowStart[node];
        int end = rowStart[node + 1];
        float4 acc = make_float4(0.f, 0.f, 0.f, 0.f);

        for (int base = beg; base < end; base += 64) {
            int nItems = min(64, end - base);
            // one coalesced load: up to 64 (src,eid) pairs for this node
            int2 pv = (lane < nItems) ? perm[base + lane] : make_int2(0, 0);

            int t = 0;
            // 16 edges per iteration: 8 independent dwordx4 loads (2KB) in flight
            for (; t + 16 <= nItems; t += 16) {
                int s0 = __shfl(pv.x, t + grp);      int e0 = __shfl(pv.y, t + grp);
                int s1 = __shfl(pv.x, t + grp + 4);  int e1 = __shfl(pv.y, t + grp + 4);
                int s2 = __shfl(pv.x, t + grp + 8);  int e2 = __shfl(pv.y, t + grp + 8);
                int s3 = __shfl(pv.x, t + grp + 12); int e3 = __shfl(pv.y, t + grp + 12);
                float4 xa = x4[(long)s0 * 16 + dl];
                float4 ma = ea4[(long)e0 * 16 + dl];
                float4 xb = x4[(long)s1 * 16 + dl];
                float4 mb = ea4[(long)e1 * 16 + dl];
                float4 xc = x4[(long)s2 * 16 + dl];
                float4 mc = ea4[(long)e2 * 16 + dl];
                float4 xd = x4[(long)s3 * 16 + dl];
                float4 md = ea4[(long)e3 * 16 + dl];
                acc.x += fmaxf(xa.x + ma.x, 0.f) + fmaxf(xb.x + mb.x, 0.f)
                       + fmaxf(xc.x + mc.x, 0.f) + fmaxf(xd.x + md.x, 0.f);
                acc.y += fmaxf(xa.y + ma.y, 0.f) + fmaxf(xb.y + mb.y, 0.f)
                       + fmaxf(xc.y + mc.y, 0.f) + fmaxf(xd.y + md.y, 0.f);
                acc.z += fmaxf(xa.z + ma.z, 0.f) + fmaxf(xb.z + mb.z, 0.f)
                       + fmaxf(xc.z + mc.z, 0.f) + fmaxf(xd.z + md.z, 0.f);
                acc.w += fmaxf(xa.w + ma.w, 0.f) + fmaxf(xb.w + mb.w, 0.f)
                       + fmaxf(xc.w + mc.w, 0.f) + fmaxf(xd.w + md.w, 0.f);
            }
            // remainder: 4 edges per step, predicated per lane-group
            for (; t < nItems; t += 4) {
                int slot = t + grp;
                bool act = slot < nItems;
                int s = __shfl(pv.x, act ? slot : 0);
                int e = __shfl(pv.y, act ? slot : 0);
                float4 xv = x4[(long)s * 16 + dl];
                float4 m  = ea4[(long)e * 16 + dl];
                if (act) {
                    acc.x += fmaxf(xv.x + m.x, 0.f);
                    acc.y += fmaxf(xv.y + m.y, 0.f);
                    acc.z += fmaxf(xv.z + m.z, 0.f);
                    acc.w += fmaxf(xv.w + m.w, 0.f);
                }
            }
        }

        // sum the 4 edge-slot groups
        acc.x += __shfl_xor(acc.x, 16); acc.y += __shfl_xor(acc.y, 16);
        acc.z += __shfl_xor(acc.z, 16); acc.w += __shfl_xor(acc.w, 16);
        acc.x += __shfl_xor(acc.x, 32); acc.y += __shfl_xor(acc.y, 32);
        acc.z += __shfl_xor(acc.z, 32); acc.w += __shfl_xor(acc.w, 32);

        // self term
        float4 xs = x4[(long)node * 16 + dl];
        acc.x += eps1 * xs.x; acc.y += eps1 * xs.y;
        acc.z += eps1 * xs.z; acc.w += eps1 * xs.w;

        // GEMM1: h[4q+c] lives in acc.c on lane q (same for all grp copies)
        float o1 = sb1[lane];
        #pragma unroll
        for (int q = 0; q < 16; ++q) {
            float h0 = __shfl(acc.x, q);
            float h1 = __shfl(acc.y, q);
            float h2 = __shfl(acc.z, q);
            float h3 = __shfl(acc.w, q);
            o1 = fmaf(h0, sW1[(4 * q + 0) * DIM + lane], o1);
            o1 = fmaf(h1, sW1[(4 * q + 1) * DIM + lane], o1);
            o1 = fmaf(h2, sW1[(4 * q + 2) * DIM + lane], o1);
            o1 = fmaf(h3, sW1[(4 * q + 3) * DIM + lane], o1);
        }
        float h = fmaxf(o1, 0.f);
        float o2 = sb2[lane];
        #pragma unroll
        for (int k = 0; k < DIM; ++k) {
            o2 = fmaf(__shfl(h, k), sW2[k * DIM + lane], o2);
        }
        out[(long)node * DIM + lane] = fmaxf(o2, 0.f);
    }
}

extern "C" void kernel_launch(void* const* d_in, const int* in_sizes, int n_in,
                              void* d_out, int out_size, void* d_ws, size_t ws_size,
                              hipStream_t stream) {
    const float* x   = (const float*)d_in[0];
    const int*   ei  = (const int*)d_in[1];
    const float* ea  = (const float*)d_in[2];
    const float* W1  = (const float*)d_in[3];
    const float* b1  = (const float*)d_in[4];
    const float* W2  = (const float*)d_in[5];
    const float* b2  = (const float*)d_in[6];
    const float* eps = (const float*)d_in[7];

    const int nNodes  = in_sizes[0] / DIM;
    const int nE      = in_sizes[1] / 2;
    const int nLayers = in_sizes[3] / (DIM * DIM);
    const int L       = nLayers - 1;   // only the last layer affects the output

    const float* W1L = W1 + (long)L * DIM * DIM;
    const float* b1L = b1 + (long)L * DIM;
    const float* W2L = W2 + (long)L * DIM * DIM;
    const float* b2L = b2 + (long)L * DIM;
    float* outp = (float*)d_out;

    // ws layout: cursor[int N] | rowStart[int N+1] | pad | perm[int2 E]
    size_t rowOff  = (size_t)nNodes * 4;
    size_t permOff = ((rowOff + (size_t)(nNodes + 1) * 4 + 7) / 8) * 8;

    int*  cursor   = (int*)d_ws;
    int*  rowStart = (int*)((char*)d_ws + rowOff);
    int2* perm     = (int2*)((char*)d_ws + permOff);

    hipMemsetAsync(cursor, 0, (size_t)nNodes * 4, stream);
    hipLaunchKernelGGL(count_kernel, dim3((nE + 255) / 256), dim3(256), 0, stream,
                       ei + nE, cursor, nE);
    hipLaunchKernelGGL(scan_kernel, dim3(1), dim3(1024), 0, stream,
                       cursor, rowStart, cursor, nNodes);
    hipLaunchKernelGGL(permute_kernel, dim3((nE + 255) / 256), dim3(256), 0, stream,
                       ei, cursor, perm, nE);

    // one node per wave
    int blocks = (nNodes + 3) / 4;
    hipLaunchKernelGGL(gather_mlp_kernel, dim3(blocks), dim3(256), 0, stream,
                       (const float4*)x, (const float4*)ea, perm, rowStart, eps + L,
                       W1L, b1L, W2L, b2L, outp, nNodes);
}

// Round 5
// 342.366 us; speedup vs baseline: 1.2197x; 1.2197x over previous
//
#include <hip/hip_runtime.h>

#define DIM 64

// ---------------- CSR build ----------------

__global__ __launch_bounds__(256)
void count_kernel(const int4* __restrict__ dst4, int* __restrict__ counts, int nE4) {
    int i = blockIdx.x * 256 + threadIdx.x;
    if (i >= nE4) return;
    int4 d = dst4[i];
    atomicAdd(&counts[d.x], 1);
    atomicAdd(&counts[d.y], 1);
    atomicAdd(&counts[d.z], 1);
    atomicAdd(&counts[d.w], 1);
}

__global__ __launch_bounds__(1024)
void scan_kernel(const int* __restrict__ counts, int* __restrict__ rowStart,
                 int* __restrict__ cursor, int n) {
    __shared__ int part[1024];
    int t = threadIdx.x;
    int chunk = (n + 1023) >> 10;
    int beg = min(t * chunk, n);
    int end = min(beg + chunk, n);
    int s = 0;
    for (int i = beg; i < end; ++i) s += counts[i];
    part[t] = s;
    __syncthreads();
    for (int off = 1; off < 1024; off <<= 1) {
        int v = (t >= off) ? part[t - off] : 0;
        __syncthreads();
        part[t] += v;
        __syncthreads();
    }
    int run = (t == 0) ? 0 : part[t - 1];
    for (int i = beg; i < end; ++i) {
        rowStart[i] = run;
        cursor[i] = run;
        run += counts[i];
    }
    if (t == 0) rowStart[n] = part[1023];
}

__global__ __launch_bounds__(256)
void permute_kernel(const int4* __restrict__ src4, const int4* __restrict__ dst4,
                    int* __restrict__ cursor, int2* __restrict__ perm, int nE4) {
    int i = blockIdx.x * 256 + threadIdx.x;
    if (i >= nE4) return;
    int4 s = src4[i];
    int4 d = dst4[i];
    int e0 = i * 4;
    int p;
    p = atomicAdd(&cursor[d.x], 1); perm[p] = make_int2(s.x, e0 + 0);
    p = atomicAdd(&cursor[d.y], 1); perm[p] = make_int2(s.y, e0 + 1);
    p = atomicAdd(&cursor[d.z], 1); perm[p] = make_int2(s.z, e0 + 2);
    p = atomicAdd(&cursor[d.w], 1); perm[p] = make_int2(s.w, e0 + 3);
}

// ---------------- gather (memory phase, NO LDS, high occupancy) ----------------
// One node per wave. grp = lane>>4 (edge slot), dl = lane&15 (dim quad).
// One coalesced perm load covers <=64 edges; uniform predicated 16-edge steps keep
// 8 independent 256B gathers (4KB) in flight per wave at 6 waves/SIMD.
__global__ __launch_bounds__(256, 6)
void gather_kernel(const float4* __restrict__ x4, const float4* __restrict__ ea4,
                   const int2* __restrict__ perm, const int* __restrict__ rowStart,
                   const float* __restrict__ epsL, float4* __restrict__ agg, int nNodes) {
    const int lane = threadIdx.x & 63;
    const int wave = threadIdx.x >> 6;
    const int grp  = lane >> 4;
    const int dl   = lane & 15;
    int node = blockIdx.x * 4 + wave;
    if (node >= nNodes) return;

    const float eps1 = 1.0f + epsL[0];
    int beg = rowStart[node];
    int end = rowStart[node + 1];
    float4 acc = make_float4(0.f, 0.f, 0.f, 0.f);

    for (int base = beg; base < end; base += 64) {
        int nItems = min(64, end - base);
        int2 pv = (lane < nItems) ? perm[base + lane] : make_int2(0, 0);

        for (int t = 0; t < nItems; t += 16) {
            int i0 = t + grp, i1 = i0 + 4, i2 = i0 + 8, i3 = i0 + 12;
            bool a0 = i0 < nItems, a1 = i1 < nItems, a2 = i2 < nItems, a3 = i3 < nItems;
            int s0 = __shfl(pv.x, a0 ? i0 : 0), e0 = __shfl(pv.y, a0 ? i0 : 0);
            int s1 = __shfl(pv.x, a1 ? i1 : 0), e1 = __shfl(pv.y, a1 ? i1 : 0);
            int s2 = __shfl(pv.x, a2 ? i2 : 0), e2 = __shfl(pv.y, a2 ? i2 : 0);
            int s3 = __shfl(pv.x, a3 ? i3 : 0), e3 = __shfl(pv.y, a3 ? i3 : 0);
            float4 xa = x4[(long)s0 * 16 + dl];
            float4 ma = ea4[(long)e0 * 16 + dl];
            float4 xb = x4[(long)s1 * 16 + dl];
            float4 mb = ea4[(long)e1 * 16 + dl];
            float4 xc = x4[(long)s2 * 16 + dl];
            float4 mc = ea4[(long)e2 * 16 + dl];
            float4 xd = x4[(long)s3 * 16 + dl];
            float4 md = ea4[(long)e3 * 16 + dl];
            if (a0) {
                acc.x += fmaxf(xa.x + ma.x, 0.f); acc.y += fmaxf(xa.y + ma.y, 0.f);
                acc.z += fmaxf(xa.z + ma.z, 0.f); acc.w += fmaxf(xa.w + ma.w, 0.f);
            }
            if (a1) {
                acc.x += fmaxf(xb.x + mb.x, 0.f); acc.y += fmaxf(xb.y + mb.y, 0.f);
                acc.z += fmaxf(xb.z + mb.z, 0.f); acc.w += fmaxf(xb.w + mb.w, 0.f);
            }
            if (a2) {
                acc.x += fmaxf(xc.x + mc.x, 0.f); acc.y += fmaxf(xc.y + mc.y, 0.f);
                acc.z += fmaxf(xc.z + mc.z, 0.f); acc.w += fmaxf(xc.w + mc.w, 0.f);
            }
            if (a3) {
                acc.x += fmaxf(xd.x + md.x, 0.f); acc.y += fmaxf(xd.y + md.y, 0.f);
                acc.z += fmaxf(xd.z + md.z, 0.f); acc.w += fmaxf(xd.w + md.w, 0.f);
            }
        }
    }

    // sum the 4 edge-slot groups
    acc.x += __shfl_xor(acc.x, 16); acc.y += __shfl_xor(acc.y, 16);
    acc.z += __shfl_xor(acc.z, 16); acc.w += __shfl_xor(acc.w, 16);
    acc.x += __shfl_xor(acc.x, 32); acc.y += __shfl_xor(acc.y, 32);
    acc.z += __shfl_xor(acc.z, 32); acc.w += __shfl_xor(acc.w, 32);

    // self term
    float4 xs = x4[(long)node * 16 + dl];
    acc.x += eps1 * xs.x; acc.y += eps1 * xs.y;
    acc.z += eps1 * xs.z; acc.w += eps1 * xs.w;

    if (grp == 0) agg[(long)node * 16 + dl] = acc;
}

// ---------------- MLP (compute phase), in place on agg rows ----------------
__global__ __launch_bounds__(256)
void mlp_kernel(const float* __restrict__ W1, const float* __restrict__ b1,
                const float* __restrict__ W2, const float* __restrict__ b2,
                float* __restrict__ io, int nNodes) {
    __shared__ float sW1[DIM * DIM];
    __shared__ float sW2[DIM * DIM];
    for (int i = threadIdx.x; i < DIM * DIM; i += blockDim.x) {
        sW1[i] = W1[i];
        sW2[i] = W2[i];
    }
    __syncthreads();
    const int lane = threadIdx.x & 63;
    const int wave = threadIdx.x >> 6;
    const float bb1 = b1[lane];
    const float bb2 = b2[lane];
    const int wavesPerBlock = blockDim.x >> 6;
    const int wavesTotal = gridDim.x * wavesPerBlock;
    for (int node = blockIdx.x * wavesPerBlock + wave; node < nNodes; node += wavesTotal) {
        float h0 = io[(long)node * DIM + lane];
        float acc = bb1;
        #pragma unroll
        for (int k = 0; k < DIM; ++k) acc = fmaf(__shfl(h0, k), sW1[k * DIM + lane], acc);
        float h1 = fmaxf(acc, 0.0f);
        float acc2 = bb2;
        #pragma unroll
        for (int k = 0; k < DIM; ++k) acc2 = fmaf(__shfl(h1, k), sW2[k * DIM + lane], acc2);
        io[(long)node * DIM + lane] = fmaxf(acc2, 0.0f);
    }
}

extern "C" void kernel_launch(void* const* d_in, const int* in_sizes, int n_in,
                              void* d_out, int out_size, void* d_ws, size_t ws_size,
                              hipStream_t stream) {
    const float* x   = (const float*)d_in[0];
    const int*   ei  = (const int*)d_in[1];
    const float* ea  = (const float*)d_in[2];
    const float* W1  = (const float*)d_in[3];
    const float* b1  = (const float*)d_in[4];
    const float* W2  = (const float*)d_in[5];
    const float* b2  = (const float*)d_in[6];
    const float* eps = (const float*)d_in[7];

    const int nNodes  = in_sizes[0] / DIM;
    const int nE      = in_sizes[1] / 2;
    const int nLayers = in_sizes[3] / (DIM * DIM);
    const int L       = nLayers - 1;   // only the last layer affects the output

    const float* W1L = W1 + (long)L * DIM * DIM;
    const float* b1L = b1 + (long)L * DIM;
    const float* W2L = W2 + (long)L * DIM * DIM;
    const float* b2L = b2 + (long)L * DIM;
    float* outp = (float*)d_out;

    // ws layout: cursor[int N] | rowStart[int N+1] | pad | perm[int2 E]
    size_t rowOff  = (size_t)nNodes * 4;
    size_t permOff = ((rowOff + (size_t)(nNodes + 1) * 4 + 7) / 8) * 8;

    int*  cursor   = (int*)d_ws;
    int*  rowStart = (int*)((char*)d_ws + rowOff);
    int2* perm     = (int2*)((char*)d_ws + permOff);

    hipMemsetAsync(cursor, 0, (size_t)nNodes * 4, stream);

    int nE4 = nE / 4;   // 800000 % 4 == 0
    hipLaunchKernelGGL(count_kernel, dim3((nE4 + 255) / 256), dim3(256), 0, stream,
                       (const int4*)(ei + nE), cursor, nE4);
    hipLaunchKernelGGL(scan_kernel, dim3(1), dim3(1024), 0, stream,
                       cursor, rowStart, cursor, nNodes);
    hipLaunchKernelGGL(permute_kernel, dim3((nE4 + 255) / 256), dim3(256), 0, stream,
                       (const int4*)ei, (const int4*)(ei + nE), cursor, perm, nE4);

    // memory phase: one node per wave, no LDS
    int gblocks = (nNodes + 3) / 4;
    hipLaunchKernelGGL(gather_kernel, dim3(gblocks), dim3(256), 0, stream,
                       (const float4*)x, (const float4*)ea, perm, rowStart, eps + L,
                       (float4*)outp, nNodes);

    // compute phase: in-place MLP
    hipLaunchKernelGGL(mlp_kernel, dim3(1024), dim3(256), 0, stream,
                       W1L, b1L, W2L, b2L, outp, nNodes);
}